// Round 6
// baseline (5172.311 us; speedup 1.0000x reference)
//
#include <hip/hip_runtime.h>
#include <hip/hip_bf16.h>

#define BATCH 1024
#define HID   512
#define OUTW  348            // 12 * (8+6+4+11)
#define NBH   (BATCH * HID)  // 524288 elements
#define NWL   (2048 * 512)   // per-layer weight elements per matrix

using short8 = __attribute__((ext_vector_type(8))) short;
using bf16x8 = __attribute__((ext_vector_type(8))) __bf16;
using f32x4  = __attribute__((ext_vector_type(4))) float;

__device__ __forceinline__ float bf2f(unsigned short u) {
  union { unsigned int i; float f; } x; x.i = ((unsigned int)u) << 16; return x.f;
}
__device__ __forceinline__ unsigned short f2bf(float f) {
  __hip_bfloat16 b = __float2bfloat16(f);
  return __builtin_bit_cast(unsigned short, b);
}
__device__ __forceinline__ float sigm(float x) { return 1.0f / (1.0f + __expf(-x)); }

__device__ __forceinline__ f32x4 mfma_bf16(short8 a, short8 b, f32x4 c) {
  return __builtin_amdgcn_mfma_f32_16x16x32_bf16(
      __builtin_bit_cast(bf16x8, a), __builtin_bit_cast(bf16x8, b), c, 0, 0, 0);
}

// ---------------- setup kernels ----------------

__global__ void k_convert(const float* __restrict__ src, unsigned short* __restrict__ dst, int n) {
  int i = (blockIdx.x * blockDim.x + threadIdx.x) * 4;
  if (i + 3 < n) {
    float4 v = *(const float4*)(src + i);
    dst[i + 0] = f2bf(v.x); dst[i + 1] = f2bf(v.y);
    dst[i + 2] = f2bf(v.z); dst[i + 3] = f2bf(v.w);
  } else {
    for (int j = 0; j < 4 && i + j < n; ++j) dst[i + j] = f2bf(src[i + j]);
  }
}

// Wqp[128][512] bf16: rows 0..63 = Wcurr, 64..127 = Wprev
__global__ void k_wqp(const float* __restrict__ Wcurr, const float* __restrict__ Wprev,
                      unsigned short* __restrict__ dst) {
  int i = blockIdx.x * blockDim.x + threadIdx.x;  // < 128*512
  int row = i >> 9, col = i & 511;
  float v = (row < 64) ? Wcurr[row * 512 + col] : Wprev[(row - 64) * 512 + col];
  dst[i] = f2bf(v);
}

__global__ void k_bias(const float* __restrict__ bih, const float* __restrict__ bhh,
                       float* __restrict__ bsum) {
  int i = blockIdx.x * blockDim.x + threadIdx.x;
  if (i < 4096) bsum[i] = bih[i] + bhh[i];
}

__global__ void k_zero(uint4* __restrict__ p, int n16) {
  int i = blockIdx.x * blockDim.x + threadIdx.x;
  if (i < n16) p[i] = make_uint4(0u, 0u, 0u, 0u);
}

// P[0][r][a] = bprev[a]
__global__ void k_p0(float* __restrict__ P, const float* __restrict__ bprev) {
  int i = blockIdx.x * blockDim.x + threadIdx.x;  // < 1024*64
  P[i] = bprev[i & 63];
}

// ---------------- persistent kernel pieces ----------------

struct PP {
  const unsigned short *Wih, *Whh, *Wqp;
  unsigned short *X, *H00, *H01, *H10, *H11;
  const float *bias, *bcurr, *bprev, *v, *Wanc, *banc;
  const float *Wc0, *bc0, *Wc1, *bc1, *Wc2, *bc2;
  float *Q, *P, *out;
  unsigned *bar;
};

// One layer-step GEMM for this block's slice: G[256 rows][32 gate-cols] with
// weights in LDS (swizzled), A from global. gate-col = c_local*4 + g.
// Epilogue: bias, 4-lane shfl gather, cell update, C in regs, h -> global.
__device__ __forceinline__ void do_gates(const char* __restrict__ lwb,
                                         const float* __restrict__ bias,
                                         int mt, int ns,
                                         const unsigned short* __restrict__ AX,
                                         const unsigned short* __restrict__ AH,
                                         unsigned short* __restrict__ Hout,
                                         float (&cc)[2][2][4]) {
  const int tid = threadIdx.x, w = tid >> 6, lane = tid & 63;
  const int l16 = lane & 15, kg = lane >> 4;
  const int arow = mt * 256 + w * 32;
  const unsigned short* ax = AX + (size_t)(arow + l16) * HID + kg * 8;
  const unsigned short* ah = AH + (size_t)(arow + l16) * HID + kg * 8;

  f32x4 acc[2][2];
  acc[0][0] = (f32x4)(0.f); acc[0][1] = (f32x4)(0.f);
  acc[1][0] = (f32x4)(0.f); acc[1][1] = (f32x4)(0.f);

  const int swz = (l16 & 7) << 4;
  const char* lw0 = lwb + (size_t)l16 * 2048;
  const char* lw1 = lwb + (size_t)(16 + l16) * 2048;

#pragma unroll
  for (int ks = 0; ks < 32; ++ks) {
    const unsigned short* s0 = (ks < 16) ? (ax + ks * 32) : (ah + (ks - 16) * 32);
    short8 a0 = *(const short8*)s0;
    short8 a1 = *(const short8*)(s0 + 16 * HID);
    const int kb = ks * 64 + kg * 16;
    short8 b0 = *(const short8*)(lw0 + (kb ^ swz));
    short8 b1 = *(const short8*)(lw1 + (kb ^ swz));
    acc[0][0] = mfma_bf16(a0, b0, acc[0][0]);
    acc[0][1] = mfma_bf16(a0, b1, acc[0][1]);
    acc[1][0] = mfma_bf16(a1, b0, acc[1][0]);
    acc[1][1] = mfma_bf16(a1, b1, acc[1][1]);
  }

  const int g = l16 & 3, cl = l16 >> 2;
#pragma unroll
  for (int n2 = 0; n2 < 2; ++n2) {
    const int cell = ns * 8 + n2 * 4 + cl;
    const float bs = bias[g * 512 + cell];
#pragma unroll
    for (int m2 = 0; m2 < 2; ++m2) {
#pragma unroll
      for (int r = 0; r < 4; ++r) {
        float val = acc[m2][n2][r] + bs;
        float gf_ = __shfl(val, (lane & ~3) + 1);
        float gg_ = __shfl(val, (lane & ~3) + 2);
        float go_ = __shfl(val, (lane & ~3) + 3);
        if (g == 0) {
          float cn = sigm(gf_) * cc[m2][n2][r] + sigm(val) * tanhf(gg_);
          float hn = sigm(go_) * tanhf(cn);
          cc[m2][n2][r] = cn;
          const int row = arow + m2 * 16 + kg * 4 + r;
          Hout[(size_t)row * HID + cell] = f2bf(hn);
        }
      }
    }
  }
}

template <int S>
__device__ __forceinline__ void cls_work(const unsigned short* __restrict__ h,
                                         const float* __restrict__ Wc,
                                         const float* __restrict__ bc,
                                         float* __restrict__ out, int obase, int b) {
  const int tid = threadIdx.x, w = tid >> 6, lane = tid & 63;
  if (w >= 4) return;
  const int r = b * 4 + w;
  short8 hv = *(const short8*)(h + (size_t)r * HID + lane * 8);
  float hf[8];
#pragma unroll
  for (int j = 0; j < 8; ++j) hf[j] = bf2f((unsigned short)hv[j]);
  float logit[S];
#pragma unroll
  for (int s = 0; s < S; ++s) {
    const float* wr = Wc + s * HID + lane * 8;
    float p = 0.f;
#pragma unroll
    for (int j = 0; j < 8; ++j) p += hf[j] * wr[j];
#pragma unroll
    for (int off = 32; off; off >>= 1) p += __shfl_xor(p, off);
    logit[s] = p + bc[s];
  }
  if (lane == 0) {
    float m = logit[0];
#pragma unroll
    for (int s = 1; s < S; ++s) m = fmaxf(m, logit[s]);
    float e[S], den = 0.f;
#pragma unroll
    for (int s = 0; s < S; ++s) { e[s] = __expf(logit[s] - m); den += e[s]; }
    float inv = 1.f / den;
#pragma unroll
    for (int s = 0; s < S; ++s) out[(size_t)r * OUTW + obase + s] = e[s] * inv;
  }
}

// [Q || Pnew] = h1[b*16..+16] @ Wqp^T   (blocks b < 64)
__device__ __forceinline__ void qp_work(const unsigned short* __restrict__ h1,
                                        const unsigned short* __restrict__ Wqp,
                                        const float* __restrict__ bcurr,
                                        const float* __restrict__ bprev,
                                        float* __restrict__ Q, float* __restrict__ P,
                                        int b, int cyc) {
  const int tid = threadIdx.x, w = tid >> 6, lane = tid & 63;
  const int l16 = lane & 15, kg = lane >> 4;
  const int r0 = b * 16;
  f32x4 acc = (f32x4)(0.f);
  const unsigned short* ap = h1 + (size_t)(r0 + l16) * HID + kg * 8;
  const unsigned short* bp = Wqp + (size_t)(w * 16 + l16) * HID + kg * 8;
#pragma unroll
  for (int ks = 0; ks < 16; ++ks) {
    short8 a = *(const short8*)(ap + ks * 32);
    short8 bb = *(const short8*)(bp + ks * 32);
    acc = mfma_bf16(a, bb, acc);
  }
  const int col = w * 16 + l16;
  const float bs = (col < 64) ? bcurr[col] : bprev[col - 64];
#pragma unroll
  for (int r = 0; r < 4; ++r) {
    const int row = r0 + kg * 4 + r;
    float val = acc[r] + bs;
    if (col < 64) Q[row * 64 + col] = val;
    else if (cyc + 1 < 12) P[(size_t)(cyc + 1) * (BATCH * 64) + row * 64 + (col - 64)] = val;
  }
}

__device__ __forceinline__ void scores_work(const PP& p, int b, int cyc) {
  const int tid = threadIdx.x, w = tid >> 6, lane = tid & 63;
  if (w >= 4) return;
  const int r = b * 4 + w;
  const float q = p.Q[r * 64 + lane];
  const float vl = p.v[lane];
  const int d0 = lane * 8;
  float xacc[8];
#pragma unroll
  for (int j = 0; j < 8; ++j) xacc[j] = p.banc[d0 + j];
  float sout = 0.f;
  for (int k = 0; k < cyc; ++k) {
    float t = tanhf(p.P[(size_t)k * (BATCH * 64) + r * 64 + lane] + q) * vl;
#pragma unroll
    for (int off = 32; off; off >>= 1) t += __shfl_xor(t, off);
    const float sk = sigm(t);
    if (lane == k) sout = sk;
#pragma unroll
    for (int j = 0; j < 8; ++j) xacc[j] += sk * p.Wanc[(d0 + j) * 11 + k];
  }
  if (lane < 11) p.out[(size_t)r * OUTW + cyc * 29 + 18 + lane] = sout;
#pragma unroll
  for (int j = 0; j < 8; ++j) p.X[(size_t)r * HID + d0 + j] = f2bf(xacc[j]);
}

// ---------------- the persistent kernel ----------------
// 256 blocks x 512 threads, cooperative. Block b: mt = (b&7)>>1 (256-row batch
// slice), ns = ((b&1... see below) (8-cell slice). Weights for both layers in
// LDS (128 KB, XOR-swizzled). C state in registers across all 48 steps.
__global__ void __launch_bounds__(512, 1) k_persist(PP p) {
  extern __shared__ char smem[];  // [2][32][1024] bf16 weights, swizzled
  const int b = blockIdx.x, tid = threadIdx.x;
  const int xcd = b & 7, idx = b >> 3;
  const int mt = xcd >> 1;                 // 0..3  (batch slice, 2 XCDs each)
  const int ns = (xcd & 1) * 32 + idx;     // 0..63 (8-cell slice)

  // stage this block's weight slice into LDS (once)
  for (int i = tid; i < 8192; i += 512) {          // short8 chunks
    const int layer = i >> 12;
    const int rem = i & 4095;
    const int lr = rem >> 7;                        // LDS row 0..31 = c*4+g
    const int kc = (rem & 127) * 8;                 // element col 0..1016
    const int grow = (lr & 3) * 512 + ns * 8 + (lr >> 2);
    const unsigned short* src = (kc < 512)
        ? p.Wih + (size_t)layer * NWL + (size_t)grow * HID + kc
        : p.Whh + (size_t)layer * NWL + (size_t)grow * HID + (kc - 512);
    short8 vdat = *(const short8*)src;
    *(short8*)(smem + layer * 65536 + lr * 2048 + ((kc * 2) ^ ((lr & 7) << 4))) = vdat;
  }
  __syncthreads();

  float c0[2][2][4] = {{{0.f}}}, c1[2][2][4] = {{{0.f}}};
  unsigned epoch = 0;
  const char* lw0 = smem;
  const char* lw1 = smem + 65536;

  auto gbar = [&]() {
    __syncthreads();
    ++epoch;
    if (tid == 0) {
      __threadfence();                      // release
      atomicAdd(p.bar, 1u);
      const unsigned tgt = epoch * 256u;
      while (__hip_atomic_load(p.bar, __ATOMIC_RELAXED, __HIP_MEMORY_SCOPE_AGENT) < tgt)
        __builtin_amdgcn_s_sleep(8);
      __threadfence();                      // acquire
    }
    __syncthreads();
  };

  // prologue: L0(step 0): reads X, h0[0](zeros) -> h0[1]
  do_gates(lw0, p.bias, mt, ns, p.X, p.H00, p.H01, c0);
  gbar();

  for (int c = 0; c < 12; ++c) {
    const int base = c * 29;
    // P1: L1(t0) || L0(t1)
    do_gates(lw1, p.bias + 2048, mt, ns, p.H01, p.H10, p.H11, c1);
    do_gates(lw0, p.bias,        mt, ns, p.X,   p.H01, p.H00, c0);
    gbar();
    // P2: L1(t1) || L0(t2) || cls8(h1(t0))
    do_gates(lw1, p.bias + 2048, mt, ns, p.H00, p.H11, p.H10, c1);
    do_gates(lw0, p.bias,        mt, ns, p.X,   p.H00, p.H01, c0);
    cls_work<8>(p.H11, p.Wc0, p.bc0, p.out, base, b);
    gbar();
    // P3: L1(t2) || L0(t3) || cls6(h1(t1))
    do_gates(lw1, p.bias + 2048, mt, ns, p.H01, p.H10, p.H11, c1);
    do_gates(lw0, p.bias,        mt, ns, p.X,   p.H01, p.H00, c0);
    cls_work<6>(p.H10, p.Wc1, p.bc1, p.out, base + 8, b);
    gbar();
    // P4: L1(t3) || cls4(h1(t2))
    do_gates(lw1, p.bias + 2048, mt, ns, p.H00, p.H11, p.H10, c1);
    cls_work<4>(p.H11, p.Wc2, p.bc2, p.out, base + 14, b);
    gbar();
    // P5: qp projection of h1(t3)
    if (b < 64) qp_work(p.H10, p.Wqp, p.bcurr, p.bprev, p.Q, p.P, b, c);
    gbar();
    // P6: scores + anchor output + X embedding
    scores_work(p, b, c);
    gbar();
    // P7: L0(t4) with new X
    if (c < 11) {
      do_gates(lw0, p.bias, mt, ns, p.X, p.H00, p.H01, c0);
      gbar();
    }
  }
}

// ---------------- launcher ----------------

extern "C" void kernel_launch(void* const* d_in, const int* in_sizes, int n_in,
                              void* d_out, int out_size, void* d_ws, size_t ws_size,
                              hipStream_t stream) {
  const float* x0    = (const float*)d_in[0];
  const float* lWih  = (const float*)d_in[1];
  const float* lWhh  = (const float*)d_in[2];
  const float* lbih  = (const float*)d_in[3];
  const float* lbhh  = (const float*)d_in[4];
  const float* Wc0   = (const float*)d_in[5];
  const float* bc0   = (const float*)d_in[6];
  const float* Wc1   = (const float*)d_in[7];
  const float* bc1   = (const float*)d_in[8];
  const float* Wc2   = (const float*)d_in[9];
  const float* bc2   = (const float*)d_in[10];
  const float* Wprev = (const float*)d_in[11];
  const float* bprev = (const float*)d_in[12];
  const float* Wcurr = (const float*)d_in[13];
  const float* bcurr = (const float*)d_in[14];
  const float* Wanc  = (const float*)d_in[15];
  const float* banc  = (const float*)d_in[16];
  const float* v     = (const float*)d_in[17];
  float* out = (float*)d_out;

  const size_t NW = 2 * (size_t)NWL;  // elements per weight tensor (both layers)

  char* ws = (char*)d_ws;
  size_t off = 0;
  auto alloc = [&](size_t bytes) { char* p = ws + off; off += (bytes + 255) & ~(size_t)255; return p; };
  unsigned short* Wih_b = (unsigned short*)alloc(NW * 2);
  unsigned short* Whh_b = (unsigned short*)alloc(NW * 2);
  unsigned short* Wqp_b = (unsigned short*)alloc(128 * 512 * 2);
  float*          biasS = (float*)alloc(4096 * 4);
  unsigned short* Xb    = (unsigned short*)alloc((size_t)NBH * 2);
  unsigned short* Hb0   = (unsigned short*)alloc(2 * (size_t)NBH * 2);
  unsigned short* Hb1   = (unsigned short*)alloc(2 * (size_t)NBH * 2);
  unsigned*       bar   = (unsigned*)alloc(256);
  float*          P     = (float*)alloc((size_t)12 * BATCH * 64 * 4);
  float*          Qb    = (float*)alloc((size_t)BATCH * 64 * 4);

  k_convert<<<dim3((NW / 4 + 255) / 256), dim3(256), 0, stream>>>(lWih, Wih_b, (int)NW);
  k_convert<<<dim3((NW / 4 + 255) / 256), dim3(256), 0, stream>>>(lWhh, Whh_b, (int)NW);
  k_convert<<<dim3((NBH / 4 + 255) / 256), dim3(256), 0, stream>>>(x0, Xb, (int)NBH);
  k_wqp<<<dim3(256), dim3(256), 0, stream>>>(Wcurr, Wprev, Wqp_b);
  k_bias<<<dim3(16), dim3(256), 0, stream>>>(lbih, lbhh, biasS);
  {
    // zero Hb0, Hb1, bar (contiguous span, 256B-aligned allocs)
    size_t zb = 2 * (size_t)NBH * 2 + 2 * (size_t)NBH * 2 + 256;
    int n16 = (int)(zb / 16);
    k_zero<<<dim3((n16 + 255) / 256), dim3(256), 0, stream>>>((uint4*)Hb0, n16);
  }
  k_p0<<<dim3(256), dim3(256), 0, stream>>>(P, bprev);

  PP pp;
  pp.Wih = Wih_b; pp.Whh = Whh_b; pp.Wqp = Wqp_b;
  pp.X = Xb;
  pp.H00 = Hb0; pp.H01 = Hb0 + NBH;
  pp.H10 = Hb1; pp.H11 = Hb1 + NBH;
  pp.bias = biasS; pp.bcurr = bcurr; pp.bprev = bprev; pp.v = v;
  pp.Wanc = Wanc; pp.banc = banc;
  pp.Wc0 = Wc0; pp.bc0 = bc0; pp.Wc1 = Wc1; pp.bc1 = bc1; pp.Wc2 = Wc2; pp.bc2 = bc2;
  pp.Q = Qb; pp.P = P; pp.out = out; pp.bar = bar;

  (void)hipFuncSetAttribute((const void*)k_persist,
                            hipFuncAttributeMaxDynamicSharedMemorySize, 131072);
  void* args[] = {&pp};
  (void)hipLaunchCooperativeKernel((const void*)k_persist, dim3(256), dim3(512),
                                   args, 131072, stream);

  (void)in_sizes; (void)n_in; (void)out_size; (void)ws_size;
}

// Round 7
// 1994.179 us; speedup vs baseline: 2.5937x; 2.5937x over previous
//
#include <hip/hip_runtime.h>
#include <hip/hip_bf16.h>

#define BATCH 1024
#define HID   512
#define OUTW  348   // 12 * (8+6+4+11)

using short8 = __attribute__((ext_vector_type(8))) short;
using bf16x8 = __attribute__((ext_vector_type(8))) __bf16;
using f32x4  = __attribute__((ext_vector_type(4))) float;

__device__ __forceinline__ float bf2f(unsigned short u) {
  union { unsigned int i; float f; } x; x.i = ((unsigned int)u) << 16; return x.f;
}
__device__ __forceinline__ unsigned short f2bf(float f) {
  __hip_bfloat16 b = __float2bfloat16(f);
  return __builtin_bit_cast(unsigned short, b);
}
__device__ __forceinline__ float sigm(float x) { return 1.0f / (1.0f + __expf(-x)); }

__device__ __forceinline__ f32x4 mfma_bf16(short8 a, short8 b, f32x4 c) {
  return __builtin_amdgcn_mfma_f32_16x16x32_bf16(
      __builtin_bit_cast(bf16x8, a), __builtin_bit_cast(bf16x8, b), c, 0, 0, 0);
}

typedef const __attribute__((address_space(1))) unsigned int* gas_p;
typedef __attribute__((address_space(3))) unsigned int* las_p;
__device__ __forceinline__ void gload16(const void* g, void* l) {
  __builtin_amdgcn_global_load_lds((gas_p)g, (las_p)l, 16, 0, 0);
}

// ---------------- setup kernels ----------------

__global__ void k_convert(const float* __restrict__ src, unsigned short* __restrict__ dst, int n) {
  int i = (blockIdx.x * blockDim.x + threadIdx.x) * 4;
  if (i + 3 < n) {
    float4 v = *(const float4*)(src + i);
    dst[i + 0] = f2bf(v.x); dst[i + 1] = f2bf(v.y);
    dst[i + 2] = f2bf(v.z); dst[i + 3] = f2bf(v.w);
  } else {
    for (int j = 0; j < 4 && i + j < n; ++j) dst[i + j] = f2bf(src[i + j]);
  }
}

// Wqp[128][512] bf16: rows 0..63 = Wcurr, 64..127 = Wprev
__global__ void k_wqp(const float* __restrict__ Wcurr, const float* __restrict__ Wprev,
                      unsigned short* __restrict__ dst) {
  int i = blockIdx.x * blockDim.x + threadIdx.x;  // < 128*512
  int row = i >> 9, col = i & 511;
  float v = (row < 64) ? Wcurr[row * 512 + col] : Wprev[(row - 64) * 512 + col];
  dst[i] = f2bf(v);
}

__global__ void k_bias(const float* __restrict__ bih, const float* __restrict__ bhh,
                       float* __restrict__ bsum) {
  int i = blockIdx.x * blockDim.x + threadIdx.x;
  if (i < 4096) bsum[i] = bih[i] + bhh[i];
}

__global__ void k_zero(uint4* __restrict__ p, int n16) {
  int i = blockIdx.x * blockDim.x + threadIdx.x;
  if (i < n16) p[i] = make_uint4(0u, 0u, 0u, 0u);
}

// P[0][r][a] = bprev[a]
__global__ void k_p0(float* __restrict__ P, const float* __restrict__ bprev) {
  int i = blockIdx.x * blockDim.x + threadIdx.x;  // < 1024*64
  P[i] = bprev[i & 63];
}

// ---------------- gates dispatch (single layer-job + optional fused classifier) ----------------
// GEMM tile: BM=64 batch x 16 cells (=64 gate rows), BK=64, K=1024 (X||H).
// 512 blocks; lb -> (mt, nt) XCD-affine: XCD = lb%8 owns nt tiles {4x..4x+3}
// (512 KB/layer/XCD weight slice, L2-resident across all 48 steps).
// Block: 256 thr (4 waves). Wave w: rows w*16..w*16+15, all 16 cells x 4 gates.

struct GJob {
  const unsigned short *X, *H, *Wih, *Whh;
  const float *bias;
  float *C;
  unsigned short *Hout;
};
struct CJob {
  const unsigned short* h;
  const float *Wc, *bc;
  float* out;
  int obase;
};

__device__ __forceinline__ void run_gemm(const GJob& j, int lb,
                                         unsigned short (*Ab)[4096],
                                         unsigned short (*Bb)[4096]) {
  const int w = threadIdx.x >> 6, lane = threadIdx.x & 63;
  // XCD-affine: nt = (lb&7)*4 + ((lb>>3)&3), mt = lb>>5  (bijective on [0,512))
  const int mt = lb >> 5;
  const int nt = (lb & 7) * 4 + ((lb >> 3) & 3);
  const int m0 = mt * 64;
  const int n0 = nt * 16;
  const int l16 = lane & 15, kg = lane >> 4;

  auto stage = [&](int kt, int buf) {
    const unsigned short* Asrc = (kt < 8) ? j.X : j.H;
    const unsigned short* Wsrc = (kt < 8) ? j.Wih : j.Whh;
    const int k0 = (kt & 7) * 64;
#pragma unroll
    for (int i = 0; i < 2; ++i) {
      int s = w * 128 + i * 64 + lane;
      int row = s >> 3;
      int ke = ((s & 7) ^ (row & 7)) << 3;  // swizzled source element offset
      gload16(Asrc + (size_t)(m0 + row) * HID + k0 + ke, &Ab[buf][(w * 128 + i * 64) * 8]);
    }
#pragma unroll
    for (int i = 0; i < 2; ++i) {
      int s = w * 128 + i * 64 + lane;
      int fr = s >> 3;                       // 0..63 = g*16+c
      int g = fr >> 4, c = fr & 15;
      int ke = ((s & 7) ^ (fr & 7)) << 3;
      gload16(Wsrc + (size_t)(g * 512 + n0 + c) * HID + k0 + ke, &Bb[buf][(w * 128 + i * 64) * 8]);
    }
  };

  f32x4 acc[4];
#pragma unroll
  for (int g = 0; g < 4; ++g) acc[g] = (f32x4)(0.0f);

  stage(0, 0);
  for (int kt = 0; kt < 16; ++kt) {
    __syncthreads();
    if (kt < 15) stage(kt + 1, (kt + 1) & 1);
    const int buf = kt & 1;
#pragma unroll
    for (int ko = 0; ko < 2; ++ko) {
      const int acb = ko * 64 + kg * 16;       // logical col byte within 128B row
      const int ar = w * 16 + l16;
      short8 a = *(const short8*)&Ab[buf][ar * 64 + ((acb ^ ((ar & 7) << 4)) >> 1)];
#pragma unroll
      for (int g = 0; g < 4; ++g) {
        const int br = g * 16 + l16;
        short8 b = *(const short8*)&Bb[buf][br * 64 + ((acb ^ ((br & 7) << 4)) >> 1)];
        acc[g] = mfma_bf16(a, b, acc[g]);
      }
    }
  }

  const int ccol = n0 + l16;
  const int crow = m0 + w * 16 + kg * 4;
  const float b0 = j.bias[ccol], b1 = j.bias[512 + ccol];
  const float b2 = j.bias[1024 + ccol], b3 = j.bias[1536 + ccol];
#pragma unroll
  for (int r = 0; r < 4; ++r) {
    const int m = crow + r;
    float gi = acc[0][r] + b0;
    float gf = acc[1][r] + b1;
    float gg = acc[2][r] + b2;
    float go = acc[3][r] + b3;
    float cold = j.C[m * HID + ccol];
    float cn = sigm(gf) * cold + sigm(gi) * tanhf(gg);
    float hn = sigm(go) * tanhf(cn);
    j.C[m * HID + ccol] = cn;
    j.Hout[m * HID + ccol] = f2bf(hn);
  }
}

template <int S>
__device__ __forceinline__ void run_cls(const CJob& c, int cb) {
  const int w = threadIdx.x >> 6, lane = threadIdx.x & 63;
#pragma unroll
  for (int i = 0; i < 8; ++i) {
    const int r = (cb * 4 + w) * 8 + i;
    short8 hv = *(const short8*)(c.h + r * HID + lane * 8);
    float hf[8];
#pragma unroll
    for (int j = 0; j < 8; ++j) hf[j] = bf2f((unsigned short)hv[j]);
    float logit[S];
#pragma unroll
    for (int s = 0; s < S; ++s) {
      const float* wr = c.Wc + s * HID + lane * 8;
      float p = 0.f;
#pragma unroll
      for (int j = 0; j < 8; ++j) p += hf[j] * wr[j];
#pragma unroll
      for (int off = 32; off; off >>= 1) p += __shfl_xor(p, off);
      logit[s] = p + c.bc[s];
    }
    if (lane == 0) {
      float m = logit[0];
#pragma unroll
      for (int s = 1; s < S; ++s) m = fmaxf(m, logit[s]);
      float e[S], den = 0.f;
#pragma unroll
      for (int s = 0; s < S; ++s) { e[s] = __expf(logit[s] - m); den += e[s]; }
      float inv = 1.0f / den;
#pragma unroll
      for (int s = 0; s < S; ++s) c.out[r * OUTW + c.obase + s] = e[s] * inv;
    }
  }
}

template <int S>
__global__ __launch_bounds__(256, 4) void k_gates1(GJob A, CJob C) {
  __shared__ unsigned short Ab[2][4096];
  __shared__ unsigned short Bb[2][4096];
  const int b = blockIdx.x;
  if (b < 512) {
    run_gemm(A, b, Ab, Bb);
  } else {
    if constexpr (S > 0) run_cls<S>(C, b - 512);
  }
}

// ---------------- anchor projections: [Q || Pnew] = h1 @ Wqp^T ----------------
__global__ __launch_bounds__(256) void k_qp(
    const unsigned short* __restrict__ h1,
    const unsigned short* __restrict__ Wqp,   // [128][512] bf16
    const float* __restrict__ bcurr, const float* __restrict__ bprev,
    float* __restrict__ Q,                    // [1024][64]
    float* __restrict__ P,                    // [12][1024][64]
    int cyc) {
  __shared__ unsigned short Ab[2][4096];
  __shared__ unsigned short Bb[2][1024];
  const int w = threadIdx.x >> 6, lane = threadIdx.x & 63;
  const int m0 = blockIdx.x * 64, n0 = blockIdx.y * 16;
  const int l16 = lane & 15, kg = lane >> 4;

  auto stage = [&](int kt, int buf) {
    const int k0 = kt * 64;
#pragma unroll
    for (int j = 0; j < 2; ++j) {
      int s = w * 128 + j * 64 + lane;
      int row = s >> 3;
      int ke = ((s & 7) ^ (row & 7)) << 3;
      gload16(h1 + (size_t)(m0 + row) * HID + k0 + ke, &Ab[buf][(w * 128 + j * 64) * 8]);
    }
    if (w < 2) {
      int s = w * 64 + lane;
      int row = s >> 3;
      int ke = ((s & 7) ^ (row & 7)) << 3;
      gload16(Wqp + (size_t)(n0 + row) * HID + k0 + ke, &Bb[buf][(w * 64) * 8]);
    }
  };

  f32x4 acc = (f32x4)(0.0f);
  stage(0, 0);
  for (int kt = 0; kt < 8; ++kt) {
    __syncthreads();
    if (kt < 7) stage(kt + 1, (kt + 1) & 1);
    const int buf = kt & 1;
#pragma unroll
    for (int ko = 0; ko < 2; ++ko) {
      const int acb = ko * 64 + kg * 16;
      const int ar = w * 16 + l16;
      short8 a = *(const short8*)&Ab[buf][ar * 64 + ((acb ^ ((ar & 7) << 4)) >> 1)];
      const int br = l16;
      short8 b = *(const short8*)&Bb[buf][br * 64 + ((acb ^ ((br & 7) << 4)) >> 1)];
      acc = mfma_bf16(a, b, acc);
    }
  }

  const int col = n0 + l16;
  const int r0 = m0 + w * 16 + kg * 4;
#pragma unroll
  for (int r = 0; r < 4; ++r) {
    const int m = r0 + r;
    float val = acc[r] + (col < 64 ? bcurr[col] : bprev[col - 64]);
    if (col < 64) Q[m * 64 + col] = val;
    else if (cyc + 1 < 12) P[(cyc + 1) * (BATCH * 64) + m * 64 + (col - 64)] = val;
  }
}

// ---------------- anchor scores + embedding ----------------
template <int CYC>
__global__ __launch_bounds__(256) void k_scores(
    const float* __restrict__ Q, const float* __restrict__ P,
    const float* __restrict__ vv, const float* __restrict__ Wanc,
    const float* __restrict__ banc, float* __restrict__ out,
    unsigned short* __restrict__ X) {
  const int w = threadIdx.x >> 6, lane = threadIdx.x & 63;
  const int r = blockIdx.x * 4 + w;
  const float q = Q[r * 64 + lane];
  const float vl = vv[lane];
  float sk[CYC > 0 ? CYC : 1];
#pragma unroll
  for (int k = 0; k < CYC; ++k) {
    float t = tanhf(P[k * (BATCH * 64) + r * 64 + lane] + q) * vl;
#pragma unroll
    for (int off = 32; off; off >>= 1) t += __shfl_xor(t, off);
    sk[k] = sigm(t);
  }
  float ov = 0.0f;
#pragma unroll
  for (int k = 0; k < 11; ++k)
    if (lane == k) ov = (k < CYC) ? sk[k] : 0.0f;
  if (lane < 11) out[r * OUTW + CYC * 29 + 18 + lane] = ov;

  const int d0 = lane * 8;
#pragma unroll
  for (int j = 0; j < 8; ++j) {
    const int d = d0 + j;
    float x = banc[d];
#pragma unroll
    for (int k = 0; k < CYC; ++k) x += sk[k] * Wanc[d * 11 + k];
    X[r * HID + d] = f2bf(x);
  }
}

// ---------------- launcher ----------------

extern "C" void kernel_launch(void* const* d_in, const int* in_sizes, int n_in,
                              void* d_out, int out_size, void* d_ws, size_t ws_size,
                              hipStream_t stream) {
  const float* x0    = (const float*)d_in[0];
  const float* lWih  = (const float*)d_in[1];
  const float* lWhh  = (const float*)d_in[2];
  const float* lbih  = (const float*)d_in[3];
  const float* lbhh  = (const float*)d_in[4];
  const float* Wc0   = (const float*)d_in[5];
  const float* bc0   = (const float*)d_in[6];
  const float* Wc1   = (const float*)d_in[7];
  const float* bc1   = (const float*)d_in[8];
  const float* Wc2   = (const float*)d_in[9];
  const float* bc2   = (const float*)d_in[10];
  const float* Wprev = (const float*)d_in[11];
  const float* bprev = (const float*)d_in[12];
  const float* Wcurr = (const float*)d_in[13];
  const float* bcurr = (const float*)d_in[14];
  const float* Wanc  = (const float*)d_in[15];
  const float* banc  = (const float*)d_in[16];
  const float* v     = (const float*)d_in[17];
  float* out = (float*)d_out;

  const size_t NW  = 2 * 2048 * 512;
  const size_t NBH = (size_t)BATCH * HID;

  char* ws = (char*)d_ws;
  size_t off = 0;
  auto alloc = [&](size_t bytes) { char* p = ws + off; off += (bytes + 255) & ~(size_t)255; return p; };
  unsigned short* Wih_b = (unsigned short*)alloc(NW * 2);
  unsigned short* Whh_b = (unsigned short*)alloc(NW * 2);
  unsigned short* Wqp_b = (unsigned short*)alloc(128 * 512 * 2);
  float*          biasS = (float*)alloc(4096 * 4);
  unsigned short* Xb    = (unsigned short*)alloc(NBH * 2);
  unsigned short* Hb0   = (unsigned short*)alloc(2 * NBH * 2);
  unsigned short* Hb1   = (unsigned short*)alloc(2 * NBH * 2);
  float*          C0    = (float*)alloc(NBH * 4);
  float*          C1    = (float*)alloc(NBH * 4);
  float*          P     = (float*)alloc((size_t)12 * BATCH * 64 * 4);
  float*          Qb    = (float*)alloc((size_t)BATCH * 64 * 4);

  k_convert<<<dim3((NW / 4 + 255) / 256), dim3(256), 0, stream>>>(lWih, Wih_b, (int)NW);
  k_convert<<<dim3((NW / 4 + 255) / 256), dim3(256), 0, stream>>>(lWhh, Whh_b, (int)NW);
  k_convert<<<dim3((NBH / 4 + 255) / 256), dim3(256), 0, stream>>>(x0, Xb, (int)NBH);
  k_wqp<<<dim3(256), dim3(256), 0, stream>>>(Wcurr, Wprev, Wqp_b);
  k_bias<<<dim3(16), dim3(256), 0, stream>>>(lbih, lbhh, biasS);
  {
    size_t zb = 2 * NBH * 2 + 2 * NBH * 2 + NBH * 4 + NBH * 4;  // Hb0,Hb1,C0,C1 contiguous
    int n16 = (int)(zb / 16);
    k_zero<<<dim3((n16 + 255) / 256), dim3(256), 0, stream>>>((uint4*)Hb0, n16);
  }
  k_p0<<<dim3(256), dim3(256), 0, stream>>>(P, bprev);

  // job builders (buffer parity: writer of step t uses parity (t+1)&1)
  auto jobL0 = [&](int u) {
    GJob j; j.X = Xb; j.H = Hb0 + (u & 1) * NBH;
    j.Wih = Wih_b; j.Whh = Whh_b; j.bias = biasS; j.C = C0;
    j.Hout = Hb0 + ((u + 1) & 1) * NBH; return j;
  };
  auto jobL1 = [&](int t) {
    GJob j; j.X = Hb0 + ((t + 1) & 1) * NBH; j.H = Hb1 + (t & 1) * NBH;
    j.Wih = Wih_b + 2048 * 512; j.Whh = Whh_b + 2048 * 512; j.bias = biasS + 2048; j.C = C1;
    j.Hout = Hb1 + ((t + 1) & 1) * NBH; return j;
  };
  auto h1of = [&](int t) { return (const unsigned short*)(Hb1 + ((t + 1) & 1) * NBH); };
  CJob nocls{};

  // prologue: L0(step 0)
  k_gates1<0><<<dim3(512), dim3(256), 0, stream>>>(jobL0(0), nocls);

  for (int c = 0; c < 12; ++c) {
    const int t0 = 4 * c, t1 = t0 + 1, t2 = t0 + 2, t3 = t0 + 3;
    const int base = c * 29;
    CJob cls0{h1of(t0), Wc0, bc0, out, base};
    CJob cls1{h1of(t1), Wc1, bc1, out, base + 8};
    CJob cls2{h1of(t2), Wc2, bc2, out, base + 14};

    k_gates1<0><<<dim3(512), dim3(256), 0, stream>>>(jobL1(t0), nocls);
    k_gates1<0><<<dim3(512), dim3(256), 0, stream>>>(jobL0(t1), nocls);
    k_gates1<8><<<dim3(544), dim3(256), 0, stream>>>(jobL1(t1), cls0);   // cls8 reads h1(t0)
    k_gates1<0><<<dim3(512), dim3(256), 0, stream>>>(jobL0(t2), nocls);
    k_gates1<6><<<dim3(544), dim3(256), 0, stream>>>(jobL1(t2), cls1);   // cls6 reads h1(t1)
    k_gates1<0><<<dim3(512), dim3(256), 0, stream>>>(jobL0(t3), nocls);
    k_gates1<4><<<dim3(544), dim3(256), 0, stream>>>(jobL1(t3), cls2);   // cls4 reads h1(t2)

    k_qp<<<dim3(16, 8), dim3(256), 0, stream>>>(h1of(t3), Wqp_b, bcurr, bprev, Qb, P, c);
    switch (c) {
      case 0:  k_scores<0><<<dim3(256), dim3(256), 0, stream>>>(Qb, P, v, Wanc, banc, out, Xb); break;
      case 1:  k_scores<1><<<dim3(256), dim3(256), 0, stream>>>(Qb, P, v, Wanc, banc, out, Xb); break;
      case 2:  k_scores<2><<<dim3(256), dim3(256), 0, stream>>>(Qb, P, v, Wanc, banc, out, Xb); break;
      case 3:  k_scores<3><<<dim3(256), dim3(256), 0, stream>>>(Qb, P, v, Wanc, banc, out, Xb); break;
      case 4:  k_scores<4><<<dim3(256), dim3(256), 0, stream>>>(Qb, P, v, Wanc, banc, out, Xb); break;
      case 5:  k_scores<5><<<dim3(256), dim3(256), 0, stream>>>(Qb, P, v, Wanc, banc, out, Xb); break;
      case 6:  k_scores<6><<<dim3(256), dim3(256), 0, stream>>>(Qb, P, v, Wanc, banc, out, Xb); break;
      case 7:  k_scores<7><<<dim3(256), dim3(256), 0, stream>>>(Qb, P, v, Wanc, banc, out, Xb); break;
      case 8:  k_scores<8><<<dim3(256), dim3(256), 0, stream>>>(Qb, P, v, Wanc, banc, out, Xb); break;
      case 9:  k_scores<9><<<dim3(256), dim3(256), 0, stream>>>(Qb, P, v, Wanc, banc, out, Xb); break;
      case 10: k_scores<10><<<dim3(256), dim3(256), 0, stream>>>(Qb, P, v, Wanc, banc, out, Xb); break;
      default: k_scores<11><<<dim3(256), dim3(256), 0, stream>>>(Qb, P, v, Wanc, banc, out, Xb); break;
    }
    if (c < 11)
      k_gates1<0><<<dim3(512), dim3(256), 0, stream>>>(jobL0(t3 + 1), nocls);
  }
  (void)in_sizes; (void)n_in; (void)out_size; (void)ws_size;
}